// Round 7
// baseline (409.650 us; speedup 1.0000x reference)
//
#include <hip/hip_runtime.h>
#include <math.h>

#define NBINS 10
#define SLOTS (NBINS + 1)   // +1 dummy bin for invalid (w==0) elements
#define NCOPY 128           // LDS histogram copies: tid & 127

typedef float  f4 __attribute__((ext_vector_type(4)));
typedef int    i4 __attribute__((ext_vector_type(4)));

// loss = (1/n_nonempty) * sum_b S_b / cnt_b   (tot cancels; weight is 0/1)
// Packed fixed-point histogram: per element ONE ds_add_u64 of
//   (1<<44) + (u32)(bce*w * 2^24)
// count in bits [44:63], sum*2^24 in [0:43]. Integer adds -> deterministic.
//
// R6 lesson: L3-hit path (~4 TB/s) is SLOWER than nt-streaming from HBM
// (~5.6 TB/s) -> all three streams non-temporal (R5 config). This round:
// fuse the finalize pass via last-block ticket (threadfence + device atomic),
// saving the second launch. Ticket counter reset each call by hipMemsetAsync.

__global__ __launch_bounds__(256) void ghmc_fused(
    const float* __restrict__ pred,
    const int*   __restrict__ target,
    const float* __restrict__ weight,
    unsigned long long* __restrict__ ws,   // [NBINS * NB] packed
    unsigned int* __restrict__ ticket,     // [1], zeroed before launch
    float* __restrict__ out,
    long long n, int NB)
{
  __shared__ unsigned long long hist[NCOPY * SLOTS];
  for (int i = threadIdx.x; i < NCOPY * SLOTS; i += 256)
    hist[i] = 0ull;
  __syncthreads();

  const int tid = threadIdx.x;
  unsigned long long* mycopy = &hist[(tid & 127) * SLOTS];

  const long long nv4    = n >> 2;
  const long long stride = (long long)gridDim.x * blockDim.x;
  const long long idx    = (long long)blockIdx.x * blockDim.x + tid;

  const f4* p4 = (const f4*)pred;
  const i4* t4 = (const i4*)target;
  const f4* w4 = (const f4*)weight;

  auto proc = [&](float pj, int tj, float wj) {
    float x    = __int_as_float(__float_as_int(pj) ^ (tj << 31)); // (1-2t)*p
    float q    = __expf(-fabsf(x));                // e^{-|x|} in (0,1]
    float onep = 1.0f + q;
    float r    = __builtin_amdgcn_rcpf(onep);
    float g    = (x >= 0.0f) ? r : q * r;          // sigmoid(x) = |sig(p)-t|
    float bw   = (fmaxf(x, 0.0f) + __logf(onep)) * wj;  // softplus(x)*w
    int bin    = min((int)(g * 10.0f), NBINS - 1);
    bin        = (wj > 0.0f) ? bin : NBINS;        // invalid -> dummy slot
    unsigned int u = (unsigned int)(bw * 16777216.0f);   // *2^24 fixed-point
    atomicAdd(&mycopy[bin], (1ull << 44) + (unsigned long long)u);
  };

  for (long long i = idx; i < nv4; i += stride) {
    f4 p = __builtin_nontemporal_load(&p4[i]);   // all streams: HBM nt
    i4 t = __builtin_nontemporal_load(&t4[i]);
    f4 w = __builtin_nontemporal_load(&w4[i]);
    proc(p.x, t.x, w.x);
    proc(p.y, t.y, w.y);
    proc(p.z, t.z, w.z);
    proc(p.w, t.w, w.w);
  }

  // scalar tail (n % 4) — zero iters for this shape; before the reduce
  if (idx == 0) {
    for (long long e = (nv4 << 2); e < n; e++)
      proc(pred[e], target[e], weight[e]);
  }
  __syncthreads();

  // reduce 128 copies -> 10 bins (dummy slot NBINS discarded)
  __shared__ unsigned long long part[NBINS][16];
  if (tid < NBINS * 16) {
    int b = tid >> 4, c = tid & 15;          // 16 chunks of 8 copies each
    unsigned long long s = 0ull;
    for (int k = 0; k < 8; k++)
      s += hist[(c * 8 + k) * SLOTS + b];
    part[b][c] = s;
  }
  __syncthreads();
  if (tid < NBINS) {
    unsigned long long s = 0ull;
    for (int c = 0; c < 16; c++) s += part[tid][c];
    ws[tid * NB + blockIdx.x] = s;
  }

  // ---- last-block ticket: release our ws writes, acquire everyone's ----
  __shared__ bool amLast;
  __threadfence();                            // device-scope release
  if (tid == 0) {
    unsigned int prev = atomicAdd(ticket, 1u);
    amLast = (prev == (unsigned int)(gridDim.x - 1));
  }
  __syncthreads();
  if (!amLast) return;
  __threadfence();                            // acquire

  // ---- finalize (deterministic fixed-order reduction, one block) ----
  const unsigned long long SMASK = (1ull << 44) - 1ull;
  double    fs[NBINS];
  long long fc[NBINS];
#pragma unroll
  for (int b = 0; b < NBINS; b++) { fs[b] = 0.0; fc[b] = 0; }

  for (int i = tid; i < NB; i += 256) {
#pragma unroll
    for (int b = 0; b < NBINS; b++) {
      unsigned long long v = ws[b * NB + i];
      fc[b] += (long long)(v >> 44);
      fs[b] += (double)(v & SMASK);
    }
  }

  __shared__ double    ssum[NBINS][4];
  __shared__ long long scnt[NBINS][4];
  int lane = tid & 63, wid = tid >> 6;
#pragma unroll
  for (int b = 0; b < NBINS; b++) {
    double    v = fs[b];
    long long c = fc[b];
    for (int off = 32; off >= 1; off >>= 1) {
      v += __shfl_down(v, off);
      c += __shfl_down(c, off);
    }
    if (lane == 0) { ssum[b][wid] = v; scnt[b][wid] = c; }
  }
  __syncthreads();

  if (tid == 0) {
    int n_ne = 0;
    double    sums[NBINS];
    long long cnts[NBINS];
#pragma unroll
    for (int b = 0; b < NBINS; b++) {
      double v = 0.0; long long c = 0;
      for (int w = 0; w < 4; w++) { v += ssum[b][w]; c += scnt[b][w]; }
      sums[b] = v; cnts[b] = c;
      n_ne += (c > 0) ? 1 : 0;
    }
    double nne  = (n_ne > 0) ? (double)n_ne : 1.0;
    double loss = 0.0;
#pragma unroll
    for (int b = 0; b < NBINS; b++) {
      if (cnts[b] > 0)
        loss += (sums[b] * (1.0 / 16777216.0)) / ((double)cnts[b] * nne);
    }
    out[0] = (float)loss;  // LOSS_WEIGHT = 1.0
  }
}

extern "C" void kernel_launch(void* const* d_in, const int* in_sizes, int n_in,
                              void* d_out, int out_size, void* d_ws, size_t ws_size,
                              hipStream_t stream)
{
  const float* pred   = (const float*)d_in[0];
  const int*   target = (const int*)d_in[1];
  const float* weight = (const float*)d_in[2];
  float* out = (float*)d_out;
  long long n = (long long)in_sizes[0];

  int NB = 2048;
  size_t per_block = (size_t)NBINS * sizeof(unsigned long long);
  size_t need = (size_t)NB * per_block + sizeof(unsigned int);
  if (ws_size < need) {
    int maxnb = (int)((ws_size - sizeof(unsigned int)) / per_block);
    NB = (maxnb < 1) ? 1 : maxnb;
  }
  unsigned long long* ws     = (unsigned long long*)d_ws;
  unsigned int*       ticket = (unsigned int*)((char*)d_ws + (size_t)NBINS * NB * sizeof(unsigned long long));

  hipMemsetAsync(ticket, 0, sizeof(unsigned int), stream);
  ghmc_fused<<<NB, 256, 0, stream>>>(pred, target, weight, ws, ticket, out, n, NB);
}

// Round 8
// 94.581 us; speedup vs baseline: 4.3312x; 4.3312x over previous
//
#include <hip/hip_runtime.h>
#include <math.h>

#define NBINS 10
#define SLOTS (NBINS + 1)   // +1 dummy bin for invalid (w==0) elements
#define NCOPY 128           // LDS histogram copies: tid & 127

typedef float  f4 __attribute__((ext_vector_type(4)));
typedef int    i4 __attribute__((ext_vector_type(4)));

// loss = (1/n_nonempty) * sum_b S_b / cnt_b   (tot cancels; weight is 0/1)
// Packed fixed-point histogram: per element ONE ds_add_u64 of
//   (1<<44) + (u32)(bce*w * 2^24)
// count in bits [44:63], sum*2^24 in [0:43]. Integer adds -> deterministic.
//
// Config notes (measured across R5-R7):
//  - all three streams NON-TEMPORAL: L3-hit path is ~4 TB/s, slower than
//    nt-streaming from HBM (~5.6-5.7 TB/s). (R6)
//  - two kernels, NOT fused: fusing finalize inflates the streaming
//    kernel's VGPR 20->56 (double accumulators), occupancy 64->35%,
//    throughput collapses to 0.57 TB/s. Keep the hot kernel skinny. (R7)
//  - R5 = 94.3 us graph ~= 90% of the 6.29 TB/s nt ceiling; mandatory
//    bytes 503 MB -> 80 us hard floor.

__global__ __launch_bounds__(256) void ghmc_partials(
    const float* __restrict__ pred,
    const int*   __restrict__ target,
    const float* __restrict__ weight,
    unsigned long long* __restrict__ ws,   // [NBINS * NB] packed
    long long n, int NB)
{
  __shared__ unsigned long long hist[NCOPY * SLOTS];
  for (int i = threadIdx.x; i < NCOPY * SLOTS; i += 256)
    hist[i] = 0ull;
  __syncthreads();

  const int tid = threadIdx.x;
  unsigned long long* mycopy = &hist[(tid & 127) * SLOTS];

  const long long nv4    = n >> 2;
  const long long stride = (long long)gridDim.x * blockDim.x;
  const long long idx    = (long long)blockIdx.x * blockDim.x + tid;

  const f4* p4 = (const f4*)pred;
  const i4* t4 = (const i4*)target;
  const f4* w4 = (const f4*)weight;

  auto proc = [&](float pj, int tj, float wj) {
    float x    = __int_as_float(__float_as_int(pj) ^ (tj << 31)); // (1-2t)*p
    float q    = __expf(-fabsf(x));                // e^{-|x|} in (0,1]
    float onep = 1.0f + q;
    float r    = __builtin_amdgcn_rcpf(onep);
    float g    = (x >= 0.0f) ? r : q * r;          // sigmoid(x) = |sig(p)-t|
    float bw   = (fmaxf(x, 0.0f) + __logf(onep)) * wj;  // softplus(x)*w
    int bin    = min((int)(g * 10.0f), NBINS - 1);
    bin        = (wj > 0.0f) ? bin : NBINS;        // invalid -> dummy slot
    unsigned int u = (unsigned int)(bw * 16777216.0f);   // *2^24 fixed-point
    atomicAdd(&mycopy[bin], (1ull << 44) + (unsigned long long)u);
  };

  for (long long i = idx; i < nv4; i += stride) {
    f4 p = __builtin_nontemporal_load(&p4[i]);   // all streams: HBM nt
    i4 t = __builtin_nontemporal_load(&t4[i]);
    f4 w = __builtin_nontemporal_load(&w4[i]);
    proc(p.x, t.x, w.x);
    proc(p.y, t.y, w.y);
    proc(p.z, t.z, w.z);
    proc(p.w, t.w, w.w);
  }

  // scalar tail (n % 4) — zero iters for this shape; before the reduce
  if (idx == 0) {
    for (long long e = (nv4 << 2); e < n; e++)
      proc(pred[e], target[e], weight[e]);
  }
  __syncthreads();

  // reduce 128 copies -> 10 bins (dummy slot NBINS discarded)
  __shared__ unsigned long long part[NBINS][16];
  if (tid < NBINS * 16) {
    int b = tid >> 4, c = tid & 15;          // 16 chunks of 8 copies each
    unsigned long long s = 0ull;
    for (int k = 0; k < 8; k++)
      s += hist[(c * 8 + k) * SLOTS + b];
    part[b][c] = s;
  }
  __syncthreads();
  if (tid < NBINS) {
    unsigned long long s = 0ull;
    for (int c = 0; c < 16; c++) s += part[tid][c];
    ws[tid * NB + blockIdx.x] = s;
  }
}

__global__ __launch_bounds__(256) void ghmc_finalize(
    const unsigned long long* __restrict__ ws,
    float* __restrict__ out, int NB)
{
  const unsigned long long SMASK = (1ull << 44) - 1ull;
  double    fs[NBINS];
  long long fc[NBINS];
#pragma unroll
  for (int b = 0; b < NBINS; b++) { fs[b] = 0.0; fc[b] = 0; }

  for (int i = threadIdx.x; i < NB; i += 256) {
#pragma unroll
    for (int b = 0; b < NBINS; b++) {
      unsigned long long v = ws[b * NB + i];
      fc[b] += (long long)(v >> 44);
      fs[b] += (double)(v & SMASK);
    }
  }

  __shared__ double    ssum[NBINS][4];
  __shared__ long long scnt[NBINS][4];
  int lane = threadIdx.x & 63, wid = threadIdx.x >> 6;
#pragma unroll
  for (int b = 0; b < NBINS; b++) {
    double    v = fs[b];
    long long c = fc[b];
    for (int off = 32; off >= 1; off >>= 1) {
      v += __shfl_down(v, off);
      c += __shfl_down(c, off);
    }
    if (lane == 0) { ssum[b][wid] = v; scnt[b][wid] = c; }
  }
  __syncthreads();

  if (threadIdx.x == 0) {
    int n_ne = 0;
    double    sums[NBINS];
    long long cnts[NBINS];
#pragma unroll
    for (int b = 0; b < NBINS; b++) {
      double v = 0.0; long long c = 0;
      for (int w = 0; w < 4; w++) { v += ssum[b][w]; c += scnt[b][w]; }
      sums[b] = v; cnts[b] = c;
      n_ne += (c > 0) ? 1 : 0;
    }
    double nne  = (n_ne > 0) ? (double)n_ne : 1.0;
    double loss = 0.0;
#pragma unroll
    for (int b = 0; b < NBINS; b++) {
      if (cnts[b] > 0)
        loss += (sums[b] * (1.0 / 16777216.0)) / ((double)cnts[b] * nne);
    }
    out[0] = (float)loss;  // LOSS_WEIGHT = 1.0
  }
}

extern "C" void kernel_launch(void* const* d_in, const int* in_sizes, int n_in,
                              void* d_out, int out_size, void* d_ws, size_t ws_size,
                              hipStream_t stream)
{
  const float* pred   = (const float*)d_in[0];
  const int*   target = (const int*)d_in[1];
  const float* weight = (const float*)d_in[2];
  float* out = (float*)d_out;
  long long n = (long long)in_sizes[0];

  int NB = 2048;
  size_t per_block = (size_t)NBINS * sizeof(unsigned long long);
  if (ws_size < (size_t)NB * per_block) {
    int maxnb = (int)(ws_size / per_block);
    NB = (maxnb < 1) ? 1 : maxnb;
  }
  unsigned long long* ws = (unsigned long long*)d_ws;

  ghmc_partials<<<NB, 256, 0, stream>>>(pred, target, weight, ws, n, NB);
  ghmc_finalize<<<1, 256, 0, stream>>>(ws, out, NB);
}